// Round 5
// baseline (234.006 us; speedup 1.0000x reference)
//
#include <hip/hip_runtime.h>

// Problem constants (fixed by the reference)
#define BATCH 256
#define CDIM  2048
#define HW    49
#define KDIM  16

// 4-float vector with only 4-byte alignment (fm rows start at c*196 B, not 16B-aligned;
// gfx950 supports unaligned global dwordx4)
typedef float f4u __attribute__((ext_vector_type(4), aligned(4)));

// Workspace (floats): wT[2048*16] at 0; pscr at 32768:
//   conv writes partials  pscr[(b*4+q)*784 + k*49 + hw]
//   mid  rewrites in place pscr[b*3136 + hw*16 + k] = BN(sum_q partial)  [reads-then-barrier-then-writes]
// Total ws = 3.34 MB (same footprint as rounds 2/3).

// ---------------------------------------------------------------------------
// prep: wT[c][k] = w16[k][c] * gamma[k]*rsqrt(var+eps)/49   (BN scale + avgpool folded)
// ---------------------------------------------------------------------------
__global__ __launch_bounds__(256) void prep_kernel(
    const float* __restrict__ w16,
    const float* __restrict__ gamma, const float* __restrict__ var,
    float* __restrict__ wT)
{
    const int idx = blockIdx.x * 256 + threadIdx.x;   // grid 128 -> 32768 threads
    const int c = idx >> 4, k = idx & 15;
    const float inv = gamma[k] * rsqrtf(var[k] + 1e-5f) * (1.0f / 49.0f);
    wT[idx] = w16[k * CDIM + c] * inv;
}

// ---------------------------------------------------------------------------
// conv: partial[q][k][hw] = sum_{c in q-strip} wT[c][k]*fm[c][hw]
// grid = BATCH*4, block = 256 (4 waves, 128 c per wave).
// lane = (cs 0..3, h4 0..15): f4u load of fm[c=..+cs][4*h4..+3]; 4-deep prefetch.
// __launch_bounds__(256,3): 170-VGPR budget so the prefetch regs actually live.
// ---------------------------------------------------------------------------
__global__ __launch_bounds__(256, 3) void conv_kernel(
    const float* __restrict__ fm, const float* __restrict__ wT,
    float* __restrict__ pscr)
{
    __shared__ __align__(16) float wL[512 * KDIM];   // [c][k] strip, 32 KB
    __shared__ __align__(16) float red[4 * 16 * 64]; // [wav][k][hw slot], 16 KB

    const int tid  = threadIdx.x;
    const int b    = blockIdx.x >> 2;
    const int q    = blockIdx.x & 3;
    const int wav  = tid >> 6;
    const int lane = tid & 63;
    const int cs   = lane >> 4;      // c within 4-c group
    const int h4   = lane & 15;      // hw quad; quads 0..12 live (12 partial)

    // stage the 512-c weight strip (coalesced float4, once)
    {
        const float4* src = (const float4*)(wT + q * 512 * KDIM);
        float4* dst = (float4*)wL;
        for (int i = tid; i < (512 * KDIM) / 4; i += 256) dst[i] = src[i];
    }
    __syncthreads();

    float4 acc[KDIM];
    #pragma unroll
    for (int k = 0; k < KDIM; ++k) acc[k] = make_float4(0.f, 0.f, 0.f, 0.f);

    const bool full = (h4 < 12);
    const bool one  = (h4 == 12);
    // lane base: c = q*512 + wav*128 + cs, hw offset 4*h4; group g advances c by 4
    const float* fp0 = fm + (size_t)b * (CDIM * HW)
                     + (size_t)(q * 512 + wav * 128 + cs) * HW + 4 * h4;

#define LOADF(dst, ptr) do { f4u _v = {0.f, 0.f, 0.f, 0.f};                 \
        if (full) _v = *(const f4u*)(ptr);                                   \
        else if (one) _v.x = (ptr)[0];                                       \
        (dst) = _v; } while (0)

    f4u fbuf0, fbuf1, fbuf2, fbuf3, fnxt0, fnxt1, fnxt2, fnxt3;
    LOADF(fbuf0, fp0 + 0 * (4 * HW));
    LOADF(fbuf1, fp0 + 1 * (4 * HW));
    LOADF(fbuf2, fp0 + 2 * (4 * HW));
    LOADF(fbuf3, fp0 + 3 * (4 * HW));

    for (int m = 0; m < 8; ++m) {
        // prefetch next 4 groups (512 FMA-issue cycles of cover below)
        if (m < 7) {
            const float* np = fp0 + (size_t)(m + 1) * 4 * (4 * HW);
            LOADF(fnxt0, np + 0 * (4 * HW));
            LOADF(fnxt1, np + 1 * (4 * HW));
            LOADF(fnxt2, np + 2 * (4 * HW));
            LOADF(fnxt3, np + 3 * (4 * HW));
        }
        const int lc0 = wav * 128 + m * 16 + cs;     // local c of group 4m
        #pragma unroll
        for (int u = 0; u < 4; ++u) {
            const float4* wrow = (const float4*)&wL[(lc0 + u * 4) * KDIM];
            float wv[16];
            *(float4*)&wv[0]  = wrow[0];
            *(float4*)&wv[4]  = wrow[1];
            *(float4*)&wv[8]  = wrow[2];
            *(float4*)&wv[12] = wrow[3];
            const f4u f = (u == 0) ? fbuf0 : (u == 1) ? fbuf1 : (u == 2) ? fbuf2 : fbuf3;
            #pragma unroll
            for (int k = 0; k < KDIM; ++k) {
                acc[k].x += wv[k] * f.x;
                acc[k].y += wv[k] * f.y;
                acc[k].z += wv[k] * f.z;
                acc[k].w += wv[k] * f.w;
            }
        }
        fbuf0 = fnxt0; fbuf1 = fnxt1; fbuf2 = fnxt2; fbuf3 = fnxt3;
    }
#undef LOADF

    // reduce over cs (lanes differing in bits 4,5) via shuffles
#define RED1(V) { float v_ = (V); v_ += __shfl_xor(v_, 16); v_ += __shfl_xor(v_, 32); (V) = v_; }
    #pragma unroll
    for (int k = 0; k < KDIM; ++k) {
        RED1(acc[k].x) RED1(acc[k].y) RED1(acc[k].z) RED1(acc[k].w)
    }
#undef RED1

    if (lane < 16) {  // cs==0 lanes hold the wave partial for (k, hw=4*h4+e)
        #pragma unroll
        for (int k = 0; k < KDIM; ++k)
            *(float4*)&red[(wav * 16 + k) * 64 + h4 * 4] = acc[k];
    }
    __syncthreads();

    // cross-wave reduce + store partial [q][k][hw] (coalesced)
    for (int p = tid; p < HW * KDIM; p += 256) {
        const int k = p / HW, hw = p - k * HW;       // p = k*49+hw
        const int a = k * 64 + hw;                   // slot h4*4+e == hw
        const float s = red[a] + red[a + 1024] + red[a + 2048] + red[a + 3072];
        pscr[(size_t)(b * 4 + q) * 784 + p] = s;
    }
}

// ---------------------------------------------------------------------------
// mid: P_bn[b][hw][k] = sum_q partial[q][k][hw] + shift[k]/49   (in-place in pscr)
// grid = BATCH, block = 256. All reads precede the barrier, writes after.
// ---------------------------------------------------------------------------
__global__ __launch_bounds__(256) void mid_kernel(
    float* __restrict__ pscr,
    const float* __restrict__ gamma, const float* __restrict__ beta,
    const float* __restrict__ mean,  const float* __restrict__ var)
{
    const int tid  = threadIdx.x;
    const size_t base = (size_t)blockIdx.x * (4 * 784);
    float s0 = 0.f, s1 = 0.f, s2 = 0.f, s3 = 0.f;

#define MIDR(SV, R) { const int j = tid + 256 * (R); if (j < 784) {          \
        const int k = j & 15, hw = j >> 4;                                   \
        const size_t src = base + k * HW + hw;                               \
        const float t = pscr[src] + pscr[src + 784] + pscr[src + 1568] + pscr[src + 2352]; \
        const float inv = gamma[k] * rsqrtf(var[k] + 1e-5f);                 \
        SV = t + (beta[k] - mean[k] * inv) * (1.0f / 49.0f); } }
    MIDR(s0, 0) MIDR(s1, 1) MIDR(s2, 2) MIDR(s3, 3)
#undef MIDR
    __syncthreads();
    if (tid < 784)               pscr[base + tid]       = s0;
    if (tid + 256 < 784)         pscr[base + tid + 256] = s1;
    if (tid + 512 < 784)         pscr[base + tid + 512] = s2;
    if (tid + 768 < 784)         pscr[base + tid + 768] = s3;
}

// ---------------------------------------------------------------------------
// bp: out[b][k][c] = sum_hw P_bn[hw][k] * fm[c][hw]
// grid = BATCH*8 (256 c per block), block = 256, 1 c per thread.
// P_bn block-uniform, never written here -> s_load; hw loop fully unrolled
// so the scalar loads hoist ahead of the FMAs. fm staged in LDS (49-stride).
// ---------------------------------------------------------------------------
__global__ __launch_bounds__(256) void bp_kernel(
    const float* __restrict__ fm, const float* __restrict__ pscr,
    float* __restrict__ out)
{
    __shared__ __align__(16) float fs[256 * HW];     // 50 KB

    const int tid = threadIdx.x;
    const int b   = blockIdx.x >> 3;
    const int oc  = (blockIdx.x & 7) * 256;

    {
        const float4* src = (const float4*)(fm + ((size_t)b * CDIM + oc) * HW);
        float4* dst = (float4*)fs;
        for (int i = tid; i < (256 * HW) / 4; i += 256) dst[i] = src[i];
    }
    __syncthreads();

    const float4* __restrict__ P4 = (const float4*)(pscr + (size_t)b * (4 * 784));

    float acc[KDIM];
    #pragma unroll
    for (int k = 0; k < KDIM; ++k) acc[k] = 0.f;

    const float* row = fs + tid * HW;
    #pragma unroll
    for (int hw = 0; hw < HW; ++hw) {
        const float fv = row[hw];
        const float4 p0 = P4[hw * 4 + 0];
        const float4 p1 = P4[hw * 4 + 1];
        const float4 p2 = P4[hw * 4 + 2];
        const float4 p3 = P4[hw * 4 + 3];
        acc[0]  += p0.x * fv; acc[1]  += p0.y * fv; acc[2]  += p0.z * fv; acc[3]  += p0.w * fv;
        acc[4]  += p1.x * fv; acc[5]  += p1.y * fv; acc[6]  += p1.z * fv; acc[7]  += p1.w * fv;
        acc[8]  += p2.x * fv; acc[9]  += p2.y * fv; acc[10] += p2.z * fv; acc[11] += p2.w * fv;
        acc[12] += p3.x * fv; acc[13] += p3.y * fv; acc[14] += p3.z * fv; acc[15] += p3.w * fv;
    }

    float* ob = out + (size_t)b * (KDIM * CDIM) + oc + tid;
    #pragma unroll
    for (int k = 0; k < KDIM; ++k) ob[k * CDIM] = acc[k];
}

extern "C" void kernel_launch(void* const* d_in, const int* in_sizes, int n_in,
                              void* d_out, int out_size, void* d_ws, size_t ws_size,
                              hipStream_t stream) {
    const float* fm    = (const float*)d_in[0];
    const float* w16   = (const float*)d_in[1];
    const float* gamma = (const float*)d_in[2];
    const float* beta  = (const float*)d_in[3];
    const float* mean  = (const float*)d_in[4];
    const float* var   = (const float*)d_in[5];
    float* out  = (float*)d_out;
    float* wT   = (float*)d_ws;                   // 32768 floats (128 KB)
    float* pscr = (float*)d_ws + CDIM * KDIM;     // 802816 floats (3.2 MB)

    prep_kernel<<<128, 256, 0, stream>>>(w16, gamma, var, wT);
    conv_kernel<<<BATCH * 4, 256, 0, stream>>>(fm, wT, pscr);
    mid_kernel<<<BATCH, 256, 0, stream>>>(pscr, gamma, beta, mean, var);
    bp_kernel<<<BATCH * 8, 256, 0, stream>>>(fm, pscr, out);
}

// Round 6
// 220.529 us; speedup vs baseline: 1.0611x; 1.0611x over previous
//
#include <hip/hip_runtime.h>

// Problem constants (fixed by the reference)
#define BATCH 256
#define CDIM  2048
#define HW    49
#define KDIM  16

#define OSTRIP 8                 // c-strips per image
#define SC     256               // c per strip
#define STRIP_B (SC * HW * 4)    // 50176 bytes per strip (== 49 * 1024)
#define NLOAD  (STRIP_B / 1024)  // 49 wave-loads of 1024 B

// async global->LDS DMA, 16 B per lane: LDS dst = base + lane*16 (linear),
// global src = per-lane address. Both 16B-aligned here.
#define GLDS(g, l) __builtin_amdgcn_global_load_lds(                        \
        (const __attribute__((address_space(1))) unsigned int*)(g),          \
        (__attribute__((address_space(3))) unsigned int*)(l), 16, 0, 0)

// Workspace (floats): wT[2048*16] at 0; pscr[2048*784] at 32768 (total 6.55 MB).
//   conv writes partials  pscr[(b*8+o)*784 + k*49 + hw]
//   mid  rewrites in place pscr[b*6272 + hw*16 + k] = BN(sum_o partial)

// ---------------------------------------------------------------------------
// prep: wT[c][k] = w16[k][c] * gamma[k]*rsqrt(var+eps)/49  (BN scale + pool folded)
// ---------------------------------------------------------------------------
__global__ __launch_bounds__(256) void prep_kernel(
    const float* __restrict__ w16,
    const float* __restrict__ gamma, const float* __restrict__ var,
    float* __restrict__ wT)
{
    const int idx = blockIdx.x * 256 + threadIdx.x;   // grid 128 -> 32768 threads
    const int c = idx >> 4, k = idx & 15;
    const float inv = gamma[k] * rsqrtf(var[k] + 1e-5f) * (1.0f / 49.0f);
    wT[idx] = w16[k * CDIM + c] * inv;
}

// ---------------------------------------------------------------------------
// conv: partial[o][k][hw] = sum_{c in 256-strip} wT[c][k]*fm[c][hw]
// grid = BATCH*8, block = 256 (4 waves, 64 c per wave).
// fm strip (50 KB) streamed to LDS via global_load_lds DMA (fire-and-forget;
// 2 blocks/CU so one block's DMA overlaps the other's compute).
// w read at wave-uniform addresses through __restrict__ global -> s_load (SGPR
// FMA operand, proven in round 2 / VGPR=36). f from LDS ds_read_b32, <=2-way.
// ---------------------------------------------------------------------------
__global__ __launch_bounds__(256) void conv_kernel(
    const float* __restrict__ fm, const float* __restrict__ wT,
    float* __restrict__ pscr)
{
    __shared__ __align__(16) float fbuf[SC * HW + 4];   // 12548 floats (~49 KB)
    __shared__ __align__(16) float red[4 * KDIM * 52];  // 3328 floats (13 KB)

    const int tid  = threadIdx.x;
    const int b    = blockIdx.x >> 3;
    const int o    = blockIdx.x & 7;
    const int wavu = __builtin_amdgcn_readfirstlane(tid >> 6);  // wave-uniform
    const int lane = tid & 63;
    const int hwi  = lane < HW ? lane : HW - 1;  // clamp: lanes>=49 broadcast-read, discarded

    // ---- DMA the strip into LDS: 49 x 1024B wave-loads, split 13/12/12/12 ----
    {
        const char* gbase = (const char*)fm
            + (size_t)b * (CDIM * HW * 4) + (size_t)o * STRIP_B;
        char* lbase = (char*)fbuf;
        const int nld = (wavu == 0) ? 13 : 12;
        for (int i = 0; i < nld; ++i) {
            const int j = wavu + 4 * i;                 // 0..48, wave-uniform
            GLDS(gbase + j * 1024 + lane * 16, lbase + j * 1024);
        }
    }
    __syncthreads();   // compiler drains vmcnt(0) before s_barrier -> strip visible

    float acc[KDIM];
    #pragma unroll
    for (int k = 0; k < KDIM; ++k) acc[k] = 0.f;

    const int cl0 = wavu * 64;                          // wave's local c-base
    const float4* __restrict__ wq = (const float4*)(wT + (size_t)((o * SC + cl0) << 4));

    #pragma unroll 8
    for (int cc = 0; cc < 64; ++cc) {
        const float fv = fbuf[(cl0 + cc) * HW + hwi];   // ds_read_b32, imm offset
        const float4 w0 = wq[cc * 4 + 0];               // uniform -> s_load_dwordx4
        const float4 w1 = wq[cc * 4 + 1];
        const float4 w2 = wq[cc * 4 + 2];
        const float4 w3 = wq[cc * 4 + 3];
        acc[0]  += w0.x * fv; acc[1]  += w0.y * fv; acc[2]  += w0.z * fv; acc[3]  += w0.w * fv;
        acc[4]  += w1.x * fv; acc[5]  += w1.y * fv; acc[6]  += w1.z * fv; acc[7]  += w1.w * fv;
        acc[8]  += w2.x * fv; acc[9]  += w2.y * fv; acc[10] += w2.z * fv; acc[11] += w2.w * fv;
        acc[12] += w3.x * fv; acc[13] += w3.y * fv; acc[14] += w3.z * fv; acc[15] += w3.w * fv;
    }

    // ---- reduce 4 wave-partials via LDS, store partial [o][k][hw] coalesced ----
    if (lane < HW) {
        #pragma unroll
        for (int k = 0; k < KDIM; ++k)
            red[wavu * (KDIM * 52) + k * 52 + lane] = acc[k];
    }
    __syncthreads();
    for (int p = tid; p < HW * KDIM; p += 256) {
        const int k = p / HW, hw = p - k * HW;
        const int a = k * 52 + hw;
        const float s = red[a] + red[a + 832] + red[a + 1664] + red[a + 2496];
        pscr[(size_t)blockIdx.x * 784 + p] = s;
    }
}

// ---------------------------------------------------------------------------
// mid: P_bn[b][hw][k] = sum_o partial[o][k][hw] + shift[k]/49  (in-place, pscr)
// grid = BATCH, block = 256. All reads precede the barrier, writes after.
// ---------------------------------------------------------------------------
__global__ __launch_bounds__(256) void mid_kernel(
    float* __restrict__ pscr,
    const float* __restrict__ gamma, const float* __restrict__ beta,
    const float* __restrict__ mean,  const float* __restrict__ var)
{
    const int tid  = threadIdx.x;
    const size_t base = (size_t)blockIdx.x * (OSTRIP * 784);
    float s0 = 0.f, s1 = 0.f, s2 = 0.f, s3 = 0.f;

#define MIDR(SV, R) { const int j = tid + 256 * (R); if (j < 784) {            \
        const int k = j & 15, hw = j >> 4;                                     \
        const size_t src = base + k * HW + hw;                                 \
        float t = 0.f;                                                         \
        _Pragma("unroll")                                                      \
        for (int oo = 0; oo < OSTRIP; ++oo) t += pscr[src + oo * 784];         \
        const float inv = gamma[k] * rsqrtf(var[k] + 1e-5f);                   \
        SV = t + (beta[k] - mean[k] * inv) * (1.0f / 49.0f); } }
    MIDR(s0, 0) MIDR(s1, 1) MIDR(s2, 2) MIDR(s3, 3)
#undef MIDR
    __syncthreads();
    if (tid < 784)        pscr[base + tid]       = s0;
    if (tid + 256 < 784)  pscr[base + tid + 256] = s1;
    if (tid + 512 < 784)  pscr[base + tid + 512] = s2;
    if (tid + 768 < 784)  pscr[base + tid + 768] = s3;
}

// ---------------------------------------------------------------------------
// bp: out[b][k][c] = sum_hw P_bn[hw][k] * fm[c][hw]
// grid = BATCH*8 (256 c per block), block = 256, 1 c per thread.
// P_bn block-uniform, never written here -> s_load; fm staged in LDS.
// (unchanged from rounds 4/5 except P base stride 6272)
// ---------------------------------------------------------------------------
__global__ __launch_bounds__(256) void bp_kernel(
    const float* __restrict__ fm, const float* __restrict__ pscr,
    float* __restrict__ out)
{
    __shared__ __align__(16) float fs[256 * HW];     // 50 KB

    const int tid = threadIdx.x;
    const int b   = blockIdx.x >> 3;
    const int oc  = (blockIdx.x & 7) * 256;

    {
        const float4* src = (const float4*)(fm + ((size_t)b * CDIM + oc) * HW);
        float4* dst = (float4*)fs;
        for (int i = tid; i < (256 * HW) / 4; i += 256) dst[i] = src[i];
    }
    __syncthreads();

    const float4* __restrict__ P4 = (const float4*)(pscr + (size_t)b * (OSTRIP * 784));

    float acc[KDIM];
    #pragma unroll
    for (int k = 0; k < KDIM; ++k) acc[k] = 0.f;

    const float* row = fs + tid * HW;
    #pragma unroll
    for (int hw = 0; hw < HW; ++hw) {
        const float fv = row[hw];
        const float4 p0 = P4[hw * 4 + 0];
        const float4 p1 = P4[hw * 4 + 1];
        const float4 p2 = P4[hw * 4 + 2];
        const float4 p3 = P4[hw * 4 + 3];
        acc[0]  += p0.x * fv; acc[1]  += p0.y * fv; acc[2]  += p0.z * fv; acc[3]  += p0.w * fv;
        acc[4]  += p1.x * fv; acc[5]  += p1.y * fv; acc[6]  += p1.z * fv; acc[7]  += p1.w * fv;
        acc[8]  += p2.x * fv; acc[9]  += p2.y * fv; acc[10] += p2.z * fv; acc[11] += p2.w * fv;
        acc[12] += p3.x * fv; acc[13] += p3.y * fv; acc[14] += p3.z * fv; acc[15] += p3.w * fv;
    }

    float* ob = out + (size_t)b * (KDIM * CDIM) + oc + tid;
    #pragma unroll
    for (int k = 0; k < KDIM; ++k) ob[k * CDIM] = acc[k];
}

extern "C" void kernel_launch(void* const* d_in, const int* in_sizes, int n_in,
                              void* d_out, int out_size, void* d_ws, size_t ws_size,
                              hipStream_t stream) {
    const float* fm    = (const float*)d_in[0];
    const float* w16   = (const float*)d_in[1];
    const float* gamma = (const float*)d_in[2];
    const float* beta  = (const float*)d_in[3];
    const float* mean  = (const float*)d_in[4];
    const float* var   = (const float*)d_in[5];
    float* out  = (float*)d_out;
    float* wT   = (float*)d_ws;                   // 32768 floats (128 KB)
    float* pscr = (float*)d_ws + CDIM * KDIM;     // 2048*784 floats (6.4 MB)

    prep_kernel<<<128, 256, 0, stream>>>(w16, gamma, var, wT);
    conv_kernel<<<BATCH * OSTRIP, 256, 0, stream>>>(fm, wT, pscr);
    mid_kernel<<<BATCH, 256, 0, stream>>>(pscr, gamma, beta, mean, var);
    bp_kernel<<<BATCH * 8, 256, 0, stream>>>(fm, pscr, out);
}